// Round 6
// baseline (919.300 us; speedup 1.0000x reference)
//
#include <hip/hip_runtime.h>

#define B_ 2
#define H_ 16
#define S_ 2048
#define D_ 64
#define QB 64
#define KT 64
#define NT (S_ / KT)
#define NTHREADS 512
#define KP 4   // stride 68 f16 = 136 B = 34 dw: measured conflict-free for b128 frags (R2/R4)

typedef _Float16 f16;
typedef _Float16 f16x8 __attribute__((ext_vector_type(8)));
typedef _Float16 f16x2 __attribute__((ext_vector_type(2)));
typedef float f32x4 __attribute__((ext_vector_type(4)));

#define MFMA16(a, b, c) __builtin_amdgcn_mfma_f32_16x16x32_f16(a, b, c, 0, 0, 0)

__device__ __forceinline__ f16x8 pack8(const float4 x0, const float4 x1) {
    f16x8 o;
    o[0] = (f16)x0.x; o[1] = (f16)x0.y; o[2] = (f16)x0.z; o[3] = (f16)x0.w;
    o[4] = (f16)x1.x; o[5] = (f16)x1.y; o[6] = (f16)x1.z; o[7] = (f16)x1.w;
    return o;
}

__global__ __launch_bounds__(NTHREADS, 8)   // pin <=64 VGPR -> keep 4 blocks/CU
void attn_kernel(const float* __restrict__ q, const float* __restrict__ k,
                 const float* __restrict__ v, const int* __restrict__ mask,
                 float* __restrict__ out)
{
    // ~35.5 KB -> 4 blocks/CU (thread-capped)
    __shared__ f16 Qsh[QB][D_ + KP];    // 64 x 68  (34-dw stride: conflict-free b128)
    __shared__ f16 Ksh[KT][D_ + KP];    // 64 x 68
    __shared__ f16 Vsh[KT][D_ + 2];     // 64 x 66  row-major (R0/R5-proven; untouched)
    __shared__ f16 Psh[QB][KT + KP];    // 64 x 68
    __shared__ float rowred[QB];
    __shared__ float rlsh[QB];

    const int tid  = threadIdx.x;
    const int wave = tid >> 6;
    const int lane = tid & 63;
    const int quad = lane >> 4;
    const int l16  = lane & 15;
    const int qi   = wave & 3;   // q 16-row block (0..3)
    const int ni   = wave >> 2;  // key/d 16-block pair selector (0..1)

    const int qb = blockIdx.x;
    const int h  = blockIdx.y;
    const int b  = blockIdx.z;
    const int bh = b * H_ + h;

    const float* Qg = q + ((size_t)bh * S_ + (size_t)qb * QB) * D_;
    const float* Kg = k + (size_t)bh * S_ * D_;
    const float* Vg = v + (size_t)bh * S_ * D_;
    const int*   Mg = mask + ((size_t)b * S_ + (size_t)qb * QB) * S_;
    float* res_out  = out + ((size_t)bh * S_ + (size_t)qb * QB) * D_;
    float* attn_out = out + (size_t)B_ * H_ * S_ * D_
                          + ((size_t)bh * S_ + (size_t)qb * QB) * S_;

    if (tid < QB) rowred[tid] = 0.f;

    // ---- stage Q (scale 1/8 folded; exact in fp16) ----
    {
        const int row = tid >> 3;
        const int c   = (tid & 7) * 8;
        const float4 q0 = *(const float4*)(Qg + row * D_ + c);
        const float4 q1 = *(const float4*)(Qg + row * D_ + c + 4);
        f16x8 o;
        o[0] = (f16)(q0.x * 0.125f); o[1] = (f16)(q0.y * 0.125f);
        o[2] = (f16)(q0.z * 0.125f); o[3] = (f16)(q0.w * 0.125f);
        o[4] = (f16)(q1.x * 0.125f); o[5] = (f16)(q1.y * 0.125f);
        o[6] = (f16)(q1.z * 0.125f); o[7] = (f16)(q1.w * 0.125f);
        *(f16x8*)&Qsh[row][c] = o;
    }
    __syncthreads();

    const int qrow0 = qi * 16 + quad * 4;
    const f16x8 a0 = *(const f16x8*)&Qsh[qi * 16 + l16][quad * 8];
    const f16x8 a1 = *(const f16x8*)&Qsh[qi * 16 + l16][32 + quad * 8];

    const int colbase = ni * 16 + l16;          // col-block A; block B at +32
    const int* mp0 = Mg + (size_t)qrow0 * S_ + colbase;

    const int skk = tid >> 3;        // staging row (0..63)
    const int sd0 = (tid & 7) * 8;   // staging d-col

    // ================= sweep 1: row sums of exp (T14 reg-prefetch) =================
    f16x8 kf;
    int mcur[8];
    {
        const float* src = Kg + (size_t)skk * D_ + sd0;
        kf = pack8(*(const float4*)src, *(const float4*)(src + 4));
#pragma unroll
        for (int r = 0; r < 4; ++r) {
            mcur[2 * r]     = mp0[(size_t)r * S_];
            mcur[2 * r + 1] = mp0[(size_t)r * S_ + 32];
        }
    }

    float psum[4] = {0.f, 0.f, 0.f, 0.f};
    for (int kt = 0; kt < NT; ++kt) {
        *(f16x8*)&Ksh[skk][sd0] = kf;           // commit (no wait: data already in regs)
        __syncthreads();                        // bar1: Ksh(kt) visible

        // issue next-tile loads (latency overlaps compute below)
        const int ktn = (kt + 1 < NT) ? kt + 1 : kt;
        const float* srcn = Kg + ((size_t)(ktn * KT + skk)) * D_ + sd0;
        const float4 x0 = *(const float4*)(srcn);
        const float4 x1 = *(const float4*)(srcn + 4);
        int mnext[8];
        const int* mpn = mp0 + ktn * KT;
#pragma unroll
        for (int r = 0; r < 4; ++r) {
            mnext[2 * r]     = mpn[(size_t)r * S_];
            mnext[2 * r + 1] = mpn[(size_t)r * S_ + 32];
        }

        const f16x8 b0a = *(const f16x8*)&Ksh[colbase][quad * 8];
        const f16x8 b0b = *(const f16x8*)&Ksh[colbase][32 + quad * 8];
        const f16x8 b1a = *(const f16x8*)&Ksh[32 + colbase][quad * 8];
        const f16x8 b1b = *(const f16x8*)&Ksh[32 + colbase][32 + quad * 8];
        f32x4 c0 = {0.f, 0.f, 0.f, 0.f};
        c0 = MFMA16(a0, b0a, c0);
        c0 = MFMA16(a1, b0b, c0);
        f32x4 c1 = {0.f, 0.f, 0.f, 0.f};
        c1 = MFMA16(a0, b1a, c1);
        c1 = MFMA16(a1, b1b, c1);
#pragma unroll
        for (int r = 0; r < 4; ++r) {
            psum[r] += (mcur[2 * r]     == 1) ? 0.f : __expf(c0[r]);
            psum[r] += (mcur[2 * r + 1] == 1) ? 0.f : __expf(c1[r]);
        }

        kf = pack8(x0, x1);                     // vmcnt wait lands here (post-compute)
#pragma unroll
        for (int r = 0; r < 8; ++r) mcur[r] = mnext[r];
        __syncthreads();                        // bar2: readers of Ksh(kt) done
    }

#pragma unroll
    for (int r = 0; r < 4; ++r) {
        psum[r] += __shfl_xor(psum[r], 1);
        psum[r] += __shfl_xor(psum[r], 2);
        psum[r] += __shfl_xor(psum[r], 4);
        psum[r] += __shfl_xor(psum[r], 8);
    }
    if (l16 == 0) {
#pragma unroll
        for (int r = 0; r < 4; ++r) atomicAdd(&rowred[qrow0 + r], psum[r]);
    }
    __syncthreads();
    if (tid < QB) rlsh[tid] = 1.0f / rowred[tid];
    __syncthreads();
    float rlq[4];
#pragma unroll
    for (int r = 0; r < 4; ++r) rlq[r] = rlsh[qrow0 + r];

    // ================= sweep 2: attn + O (T14 reg-prefetch, 3 barriers/tile) =================
    f16x2 vf0, vf1, vf2, vf3;
    {
        const float* srck = Kg + (size_t)skk * D_ + sd0;
        kf = pack8(*(const float4*)srck, *(const float4*)(srck + 4));
        const float* srcv = Vg + (size_t)skk * D_ + sd0;
        const float4 y0 = *(const float4*)(srcv);
        const float4 y1 = *(const float4*)(srcv + 4);
        vf0[0] = (f16)y0.x; vf0[1] = (f16)y0.y;
        vf1[0] = (f16)y0.z; vf1[1] = (f16)y0.w;
        vf2[0] = (f16)y1.x; vf2[1] = (f16)y1.y;
        vf3[0] = (f16)y1.z; vf3[1] = (f16)y1.w;
#pragma unroll
        for (int r = 0; r < 4; ++r) {
            mcur[2 * r]     = mp0[(size_t)r * S_];
            mcur[2 * r + 1] = mp0[(size_t)r * S_ + 32];
        }
    }

    f32x4 oaccA = {0.f, 0.f, 0.f, 0.f};
    f32x4 oaccB = {0.f, 0.f, 0.f, 0.f};
    float* ap0 = attn_out + (size_t)qrow0 * S_ + colbase;

    for (int kt = 0; kt < NT; ++kt) {
        // commit prefetched K,V (regs ready; no memory wait)
        *(f16x8*)&Ksh[skk][sd0] = kf;
        *(f16x2*)&Vsh[skk][sd0]     = vf0;
        *(f16x2*)&Vsh[skk][sd0 + 2] = vf1;
        *(f16x2*)&Vsh[skk][sd0 + 4] = vf2;
        *(f16x2*)&Vsh[skk][sd0 + 6] = vf3;
        __syncthreads();                        // bar1: K/V(kt) visible

        // issue next-tile loads (overlap scores + PV)
        const int ktn = (kt + 1 < NT) ? kt + 1 : kt;
        const float* srck = Kg + ((size_t)(ktn * KT + skk)) * D_ + sd0;
        const float4 x0 = *(const float4*)(srck);
        const float4 x1 = *(const float4*)(srck + 4);
        const float* srcv = Vg + ((size_t)(ktn * KT + skk)) * D_ + sd0;
        const float4 y0 = *(const float4*)(srcv);
        const float4 y1 = *(const float4*)(srcv + 4);
        int mnext[8];
        const int* mpn = mp0 + ktn * KT;
#pragma unroll
        for (int r = 0; r < 4; ++r) {
            mnext[2 * r]     = mpn[(size_t)r * S_];
            mnext[2 * r + 1] = mpn[(size_t)r * S_ + 32];
        }

        // scores (recompute), both 16-col blocks
        const f16x8 b0a = *(const f16x8*)&Ksh[colbase][quad * 8];
        const f16x8 b0b = *(const f16x8*)&Ksh[colbase][32 + quad * 8];
        const f16x8 b1a = *(const f16x8*)&Ksh[32 + colbase][quad * 8];
        const f16x8 b1b = *(const f16x8*)&Ksh[32 + colbase][32 + quad * 8];
        f32x4 c0 = {0.f, 0.f, 0.f, 0.f};
        c0 = MFMA16(a0, b0a, c0);
        c0 = MFMA16(a1, b0b, c0);
        f32x4 c1 = {0.f, 0.f, 0.f, 0.f};
        c1 = MFMA16(a0, b1a, c1);
        c1 = MFMA16(a1, b1b, c1);
        float* ap = ap0 + kt * KT;
#pragma unroll
        for (int r = 0; r < 4; ++r) {
            const float e0 = (mcur[2 * r]     == 1) ? 0.f : __expf(c0[r]);
            const float e1 = (mcur[2 * r + 1] == 1) ? 0.f : __expf(c1[r]);
            const float p0 = e0 * rlq[r];
            const float p1 = e1 * rlq[r];
            ap[(size_t)r * S_]      = p0;           // attn output
            ap[(size_t)r * S_ + 32] = p1;
            Psh[qrow0 + r][colbase]      = (f16)p0;
            Psh[qrow0 + r][colbase + 32] = (f16)p1;
        }
        __syncthreads();                        // bar2: Psh visible; Ksh readers done

        // PV
        const f16x8 pa0 = *(const f16x8*)&Psh[qi * 16 + l16][quad * 8];
        const f16x8 pa1 = *(const f16x8*)&Psh[qi * 16 + l16][32 + quad * 8];
        f16x8 vb0a, vb1a, vb0b, vb1b;
        const int dcolA = colbase;
        const int dcolB = colbase + 32;
#pragma unroll
        for (int j = 0; j < 8; ++j) {
            vb0a[j] = Vsh[quad * 8 + j][dcolA];
            vb1a[j] = Vsh[32 + quad * 8 + j][dcolA];
            vb0b[j] = Vsh[quad * 8 + j][dcolB];
            vb1b[j] = Vsh[32 + quad * 8 + j][dcolB];
        }
        oaccA = MFMA16(pa0, vb0a, oaccA);
        oaccA = MFMA16(pa1, vb1a, oaccA);
        oaccB = MFMA16(pa0, vb0b, oaccB);
        oaccB = MFMA16(pa1, vb1b, oaccB);

        // convert next tile (vmcnt wait lands here, after all compute)
        kf = pack8(x0, x1);
        vf0[0] = (f16)y0.x; vf0[1] = (f16)y0.y;
        vf1[0] = (f16)y0.z; vf1[1] = (f16)y0.w;
        vf2[0] = (f16)y1.x; vf2[1] = (f16)y1.y;
        vf3[0] = (f16)y1.z; vf3[1] = (f16)y1.w;
#pragma unroll
        for (int r = 0; r < 8; ++r) mcur[r] = mnext[r];
        __syncthreads();                        // bar3: Psh/Vsh readers done
    }

    // res: rows qrow0+r, cols colbase and colbase+32 (1/l folded into P)
#pragma unroll
    for (int r = 0; r < 4; ++r) {
        res_out[(size_t)(qrow0 + r) * D_ + colbase]      = oaccA[r];
        res_out[(size_t)(qrow0 + r) * D_ + colbase + 32] = oaccB[r];
    }
}

extern "C" void kernel_launch(void* const* d_in, const int* in_sizes, int n_in,
                              void* d_out, int out_size, void* d_ws, size_t ws_size,
                              hipStream_t stream) {
    (void)in_sizes; (void)n_in; (void)out_size; (void)d_ws; (void)ws_size;
    const float* q   = (const float*)d_in[0];
    const float* k   = (const float*)d_in[1];
    const float* v   = (const float*)d_in[2];
    const int*  mask = (const int*)d_in[3];
    float* out = (float*)d_out;
    dim3 grid(S_ / QB, H_, B_);   // 32 x 16 x 2 = 1024 = 4 blocks/CU exactly
    attn_kernel<<<grid, dim3(NTHREADS), 0, stream>>>(q, k, v, mask, out);
}

// Round 7
// 817.538 us; speedup vs baseline: 1.1245x; 1.1245x over previous
//
#include <hip/hip_runtime.h>

#define B_ 2
#define H_ 16
#define S_ 2048
#define D_ 64
#define QB 64
#define KT 64
#define NTHREADS 512
#define KP 4   // stride 68 f16 = 136 B = 34 dw: measured conflict-free for b128 frags (R2/R4/R6)

typedef _Float16 f16;
typedef _Float16 f16x8 __attribute__((ext_vector_type(8)));
typedef _Float16 f16x4 __attribute__((ext_vector_type(4)));
typedef _Float16 f16x2 __attribute__((ext_vector_type(2)));
typedef float f32x4 __attribute__((ext_vector_type(4)));

#define MFMA16(a, b, c) __builtin_amdgcn_mfma_f32_16x16x32_f16(a, b, c, 0, 0, 0)

__global__ __launch_bounds__(NTHREADS)
void attn_kernel(const float* __restrict__ q, const float* __restrict__ k,
                 const float* __restrict__ v, const int* __restrict__ mask,
                 float* __restrict__ out)
{
    // ~35.5 KB -> 4 blocks/CU (thread-capped). R5 structure; pads 72->68 (R6-proven 0-conflict).
    __shared__ f16 Qsh[QB][D_ + KP];    // 64 x 68
    __shared__ f16 Ksh[KT][D_ + KP];    // 64 x 68
    __shared__ f16 Vsh[KT][D_ + 2];     // 64 x 66 row-major (untouched)
    __shared__ f16 Psh[QB][KT + KP];    // 64 x 68
    __shared__ float rowred[QB];
    __shared__ float rlsh[QB];

    const int tid  = threadIdx.x;
    const int wave = tid >> 6;
    const int lane = tid & 63;
    const int quad = lane >> 4;
    const int l16  = lane & 15;
    const int qi   = wave & 3;   // q 16-row block (0..3)
    const int ni   = wave >> 2;  // key/d 16-block pair selector (0..1)

    const int qb = blockIdx.x;
    const int h  = blockIdx.y;
    const int b  = blockIdx.z;
    const int bh = b * H_ + h;

    const float* Qg = q + ((size_t)bh * S_ + (size_t)qb * QB) * D_;
    const float* Kg = k + (size_t)bh * S_ * D_;
    const float* Vg = v + (size_t)bh * S_ * D_;
    const int*   Mg = mask + ((size_t)b * S_ + (size_t)qb * QB) * S_;
    float* res_out  = out + ((size_t)bh * S_ + (size_t)qb * QB) * D_;
    float* attn_out = out + (size_t)B_ * H_ * S_ * D_
                          + ((size_t)bh * S_ + (size_t)qb * QB) * S_;

    if (tid < QB) rowred[tid] = 0.f;

    // ---- stage Q (scale 1/8 folded; exact in fp16). 512 thr x 8 floats = 64x64 ----
    {
        const int row = tid >> 3;
        const int c   = (tid & 7) * 8;
        const float4 q0 = *(const float4*)(Qg + row * D_ + c);
        const float4 q1 = *(const float4*)(Qg + row * D_ + c + 4);
        f16x8 o;
        o[0] = (f16)(q0.x * 0.125f); o[1] = (f16)(q0.y * 0.125f);
        o[2] = (f16)(q0.z * 0.125f); o[3] = (f16)(q0.w * 0.125f);
        o[4] = (f16)(q1.x * 0.125f); o[5] = (f16)(q1.y * 0.125f);
        o[6] = (f16)(q1.z * 0.125f); o[7] = (f16)(q1.w * 0.125f);
        *(f16x8*)&Qsh[row][c] = o;
    }
    __syncthreads();

    // hoisted A-fragments: A[m=l16][k=quad*8+j], K=64 -> two frags
    const int qrow0 = qi * 16 + quad * 4;
    const f16x8 a0 = *(const f16x8*)&Qsh[qi * 16 + l16][quad * 8];
    const f16x8 a1 = *(const f16x8*)&Qsh[qi * 16 + l16][32 + quad * 8];

    const int colbase = ni * 16 + l16;          // col-block A; block B at +32
    const int* mp0 = Mg + (size_t)qrow0 * S_ + colbase;

    const int skk = tid >> 3;        // staging row (0..63)
    const int sd0 = (tid & 7) * 8;   // staging d-col

    // ================= sweep 1: row sums of exp =================
    float psum[4] = {0.f, 0.f, 0.f, 0.f};
    for (int kt = 0; kt < S_ / KT; ++kt) {
        {
            const float* src = Kg + ((size_t)(kt * KT + skk)) * D_ + sd0;
            const float4 x0 = *(const float4*)(src);
            const float4 x1 = *(const float4*)(src + 4);
            f16x8 o;
            o[0] = (f16)x0.x; o[1] = (f16)x0.y; o[2] = (f16)x0.z; o[3] = (f16)x0.w;
            o[4] = (f16)x1.x; o[5] = (f16)x1.y; o[6] = (f16)x1.z; o[7] = (f16)x1.w;
            *(f16x8*)&Ksh[skk][sd0] = o;
        }
        __syncthreads();
        const f16x8 b0a = *(const f16x8*)&Ksh[colbase][quad * 8];
        const f16x8 b0b = *(const f16x8*)&Ksh[colbase][32 + quad * 8];
        const f16x8 b1a = *(const f16x8*)&Ksh[32 + colbase][quad * 8];
        const f16x8 b1b = *(const f16x8*)&Ksh[32 + colbase][32 + quad * 8];
        f32x4 c0 = {0.f, 0.f, 0.f, 0.f};
        c0 = MFMA16(a0, b0a, c0);
        c0 = MFMA16(a1, b0b, c0);
        f32x4 c1 = {0.f, 0.f, 0.f, 0.f};
        c1 = MFMA16(a0, b1a, c1);
        c1 = MFMA16(a1, b1b, c1);
        const int* mp = mp0 + kt * KT;
#pragma unroll
        for (int r = 0; r < 4; ++r) {
            const int m0 = mp[(size_t)r * S_];
            const int m1 = mp[(size_t)r * S_ + 32];
            psum[r] += (m0 == 1) ? 0.f : __expf(c0[r]);
            psum[r] += (m1 == 1) ? 0.f : __expf(c1[r]);
        }
        __syncthreads();
    }

    // reduce psum across the 16 column-lanes of each quad
#pragma unroll
    for (int r = 0; r < 4; ++r) {
        psum[r] += __shfl_xor(psum[r], 1);
        psum[r] += __shfl_xor(psum[r], 2);
        psum[r] += __shfl_xor(psum[r], 4);
        psum[r] += __shfl_xor(psum[r], 8);
    }
    if (l16 == 0) {
#pragma unroll
        for (int r = 0; r < 4; ++r) atomicAdd(&rowred[qrow0 + r], psum[r]);
    }
    __syncthreads();
    if (tid < QB) rlsh[tid] = 1.0f / rowred[tid];
    __syncthreads();
    float rlq[4];
#pragma unroll
    for (int r = 0; r < 4; ++r) rlq[r] = rlsh[qrow0 + r];

    // ================= sweep 2: write attn, accumulate O =================
    f32x4 oaccA = {0.f, 0.f, 0.f, 0.f};
    f32x4 oaccB = {0.f, 0.f, 0.f, 0.f};
    float* ap0 = attn_out + (size_t)qrow0 * S_ + colbase;

    for (int kt = 0; kt < S_ / KT; ++kt) {
        {
            const float* srck = Kg + ((size_t)(kt * KT + skk)) * D_ + sd0;
            const float4 x0 = *(const float4*)(srck);
            const float4 x1 = *(const float4*)(srck + 4);
            f16x8 o;
            o[0] = (f16)x0.x; o[1] = (f16)x0.y; o[2] = (f16)x0.z; o[3] = (f16)x0.w;
            o[4] = (f16)x1.x; o[5] = (f16)x1.y; o[6] = (f16)x1.z; o[7] = (f16)x1.w;
            *(f16x8*)&Ksh[skk][sd0] = o;

            const float* srcv = Vg + ((size_t)(kt * KT + skk)) * D_ + sd0;
            const float4 y0 = *(const float4*)(srcv);
            const float4 y1 = *(const float4*)(srcv + 4);
            f16x2 p01, p23, p45, p67;
            p01[0] = (f16)y0.x; p01[1] = (f16)y0.y;
            p23[0] = (f16)y0.z; p23[1] = (f16)y0.w;
            p45[0] = (f16)y1.x; p45[1] = (f16)y1.y;
            p67[0] = (f16)y1.z; p67[1] = (f16)y1.w;
            *(f16x2*)&Vsh[skk][sd0]     = p01;
            *(f16x2*)&Vsh[skk][sd0 + 2] = p23;
            *(f16x2*)&Vsh[skk][sd0 + 4] = p45;
            *(f16x2*)&Vsh[skk][sd0 + 6] = p67;
        }
        __syncthreads();
        // scores (recompute), both 16-col blocks
        const f16x8 b0a = *(const f16x8*)&Ksh[colbase][quad * 8];
        const f16x8 b0b = *(const f16x8*)&Ksh[colbase][32 + quad * 8];
        const f16x8 b1a = *(const f16x8*)&Ksh[32 + colbase][quad * 8];
        const f16x8 b1b = *(const f16x8*)&Ksh[32 + colbase][32 + quad * 8];
        f32x4 c0 = {0.f, 0.f, 0.f, 0.f};
        c0 = MFMA16(a0, b0a, c0);
        c0 = MFMA16(a1, b0b, c0);
        f32x4 c1 = {0.f, 0.f, 0.f, 0.f};
        c1 = MFMA16(a0, b1a, c1);
        c1 = MFMA16(a1, b1b, c1);
        const int* mp = mp0 + kt * KT;
        float* ap = ap0 + kt * KT;
#pragma unroll
        for (int r = 0; r < 4; ++r) {
            const int m0 = mp[(size_t)r * S_];
            const int m1 = mp[(size_t)r * S_ + 32];
            const float e0 = (m0 == 1) ? 0.f : __expf(c0[r]);
            const float e1 = (m1 == 1) ? 0.f : __expf(c1[r]);
            const float p0 = e0 * rlq[r];
            const float p1 = e1 * rlq[r];
            ap[(size_t)r * S_]      = p0;           // attn output
            ap[(size_t)r * S_ + 32] = p1;
            Psh[qrow0 + r][colbase]      = (f16)p0; // C-layout -> A-layout via LDS
            Psh[qrow0 + r][colbase + 32] = (f16)p1;
        }
        __syncthreads();
        // PV: wave tile (qi rows; d-cols colbase and colbase+32)
        const f16x8 pa0 = *(const f16x8*)&Psh[qi * 16 + l16][quad * 8];
        const f16x8 pa1 = *(const f16x8*)&Psh[qi * 16 + l16][32 + quad * 8];
        f16x8 vb0a, vb1a, vb0b, vb1b;
        const int dcolA = colbase;
        const int dcolB = colbase + 32;
#pragma unroll
        for (int j = 0; j < 8; ++j) {
            vb0a[j] = Vsh[quad * 8 + j][dcolA];
            vb1a[j] = Vsh[32 + quad * 8 + j][dcolA];
            vb0b[j] = Vsh[quad * 8 + j][dcolB];
            vb1b[j] = Vsh[32 + quad * 8 + j][dcolB];
        }
        oaccA = MFMA16(pa0, vb0a, oaccA);
        oaccA = MFMA16(pa1, vb1a, oaccA);
        oaccB = MFMA16(pa0, vb0b, oaccB);
        oaccB = MFMA16(pa1, vb1b, oaccB);
        __syncthreads();
    }

    // res: rows qrow0+r, cols colbase and colbase+32 (1/l folded into P)
#pragma unroll
    for (int r = 0; r < 4; ++r) {
        res_out[(size_t)(qrow0 + r) * D_ + colbase]      = oaccA[r];
        res_out[(size_t)(qrow0 + r) * D_ + colbase + 32] = oaccB[r];
    }
}

extern "C" void kernel_launch(void* const* d_in, const int* in_sizes, int n_in,
                              void* d_out, int out_size, void* d_ws, size_t ws_size,
                              hipStream_t stream) {
    (void)in_sizes; (void)n_in; (void)out_size; (void)d_ws; (void)ws_size;
    const float* q   = (const float*)d_in[0];
    const float* k   = (const float*)d_in[1];
    const float* v   = (const float*)d_in[2];
    const int*  mask = (const int*)d_in[3];
    float* out = (float*)d_out;
    dim3 grid(S_ / QB, H_, B_);   // 32 x 16 x 2 = 1024 = 4 blocks/CU exactly, no tail
    attn_kernel<<<grid, dim3(NTHREADS), 0, stream>>>(q, k, v, mask, out);
}